// Round 10
// baseline (224.995 us; speedup 1.0000x reference)
//
#include <hip/hip_runtime.h>
#include <cstdint>
#include <cstddef>

// GNN: SAGEConv(mean) + GATConv(1 head, self-loops) + log_softmax
// CSR via two-level counting sort. Edge kernels: 16-lane-group per node,
// LDS-staged offsets, fp8 e4m3 rows, zero-row branchless tails.
// R10: k_gather runs two channel-half passes so the active gather window
// (3.2 MB) fits per-XCD L2. MFMA node GEMMs. 7 dispatches + memset.

typedef unsigned short ushort_t;
typedef unsigned int uint_t;
typedef __attribute__((ext_vector_type(8))) short short8;
typedef __attribute__((ext_vector_type(4))) float f32x4;
typedef __attribute__((ext_vector_type(2))) float f32x2;

__device__ inline ushort_t f2bf(float f) {
    uint_t u = __float_as_uint(f);
    uint_t r = (u + 0x7fffu + ((u >> 16) & 1u)) >> 16;   // RTNE
    return (ushort_t)r;
}

#define PART_CHUNK 16384   // edges per block in cnt / k_part

// ---------------- P0: cvt x -> bf16+fp8, weights -> bf16^T, bucket counts ----------------

__global__ __launch_bounds__(256) void k_pre(const float* __restrict__ x, ushort_t* __restrict__ xh,
                                             unsigned char* __restrict__ xq,
                                             const int* __restrict__ ei, int* __restrict__ tot,
                                             const float* __restrict__ Wl, const float* __restrict__ Wr,
                                             const float* __restrict__ Wg,
                                             ushort_t* __restrict__ Wlrt, ushort_t* __restrict__ Wgt,
                                             unsigned char* __restrict__ zq,
                                             int n4, int E, int NB, int N, int nchunk) {
    __shared__ int h[512];
    int bid = blockIdx.x, tid = threadIdx.x;
    int idx = bid * 256 + tid;
    if (idx < n4) {
        float4 v = ((const float4*)x)[idx];
        ushort4 o = { f2bf(v.x), f2bf(v.y), f2bf(v.z), f2bf(v.w) };
        ((ushort4*)xh)[idx] = o;
        int r = 0;
        r = __builtin_amdgcn_cvt_pk_fp8_f32(v.x, v.y, r, false);
        r = __builtin_amdgcn_cvt_pk_fp8_f32(v.z, v.w, r, true);
        ((uint_t*)xq)[idx] = (uint_t)r;
    }
    if (bid < nchunk) {                         // block-uniform branch: bucket histogram
        for (int b = tid; b < NB; b += 256) h[b] = 0;
        __syncthreads();
        int b0 = bid * PART_CHUNK;
        int b1 = min(b0 + PART_CHUNK, E);
        for (int j = b0 + tid; j < b1; j += 256) atomicAdd(&h[ei[E + j] >> 8], 1);
        __syncthreads();
        for (int b = tid; b < NB; b += 256) if (h[b]) atomicAdd(&tot[b], h[b]);
    } else if (bid == nchunk) {                 // zero rows (branchless tails elsewhere)
        if (tid < 16) ((uint_t*)(xq + (size_t)N * 64))[tid] = 0;
        if (tid < 8)  ((uint_t*)(zq + (size_t)N * 32))[tid] = 0;
    } else if (bid >= 512 && bid < 544) {       // weights -> bf16 transposed [n][k]
        int t = (bid - 512) * 256 + tid;        // 0..8191
        int n = t >> 7, k = t & 127;
        float v = (k < 64) ? Wl[k * 64 + n] : Wr[(k - 64) * 64 + n];
        Wlrt[n * 128 + k] = f2bf(v);
        if (t < 32 * 64) {
            int n2 = t >> 6, k2 = t & 63;
            Wgt[n2 * 64 + k2] = f2bf(Wg[k2 * 32 + n2]);
        }
    }
}

// ---------------- P1: exclusive scan of bucket totals ----------------

__global__ __launch_bounds__(256) void k_scan(const int* __restrict__ tot, int* __restrict__ base,
                                              int* __restrict__ gofs, int* __restrict__ rowptr,
                                              int NB, int E, int N) {
    __shared__ int t[256];
    int tid = threadIdx.x;
    int v0 = (2 * tid < NB) ? tot[2 * tid] : 0;
    int v1 = (2 * tid + 1 < NB) ? tot[2 * tid + 1] : 0;
    t[tid] = v0 + v1;
    __syncthreads();
    for (int off = 1; off < 256; off <<= 1) {
        int u = (tid >= off) ? t[tid - off] : 0;
        __syncthreads();
        t[tid] += u;
        __syncthreads();
    }
    int pairExcl = (tid > 0) ? t[tid - 1] : 0;
    if (2 * tid < NB)     { base[2 * tid] = pairExcl;          gofs[2 * tid] = pairExcl; }
    if (2 * tid + 1 < NB) { base[2 * tid + 1] = pairExcl + v0; gofs[2 * tid + 1] = pairExcl + v0; }
    if (tid == 0) { rowptr[N] = E; base[NB] = E; }
}

// ---------------- P2: partition (src | (dst&255)<<24) bucket-contiguous ----------------

__global__ __launch_bounds__(256) void k_part(const int* __restrict__ ei, int* __restrict__ gofs,
                                              uint_t* __restrict__ pairs, int E, int NB) {
    __shared__ int h[512];
    __shared__ int ofs[512];
    int tid = threadIdx.x;
    for (int b = tid; b < NB; b += 256) h[b] = 0;
    __syncthreads();
    int b0 = blockIdx.x * PART_CHUNK;
    int b1 = min(b0 + PART_CHUNK, E);
    for (int j = b0 + tid; j < b1; j += 256) atomicAdd(&h[ei[E + j] >> 8], 1);
    __syncthreads();
    for (int b = tid; b < NB; b += 256) ofs[b] = h[b] ? atomicAdd(&gofs[b], h[b]) : 0;
    __syncthreads();
    for (int j = b0 + tid; j < b1; j += 256) {
        int d = ei[E + j], s = ei[j];
        int p = atomicAdd(&ofs[d >> 8], 1);
        pairs[p] = (uint_t)s | ((uint_t)(d & 255) << 24);
    }
}

// ---------------- P3: per-bucket CSR build (windowed, L2-hot) ----------------

__global__ __launch_bounds__(256) void k_csr(const uint_t* __restrict__ pairs, const int* __restrict__ base,
                                             int* __restrict__ rowptr, int* __restrict__ csr, int N) {
    __shared__ int h[256];
    __shared__ int s[256];
    int b = blockIdx.x;
    int d0 = b << 8;
    int e0 = base[b], e1 = base[b + 1];
    int tid = threadIdx.x;
    h[tid] = 0;
    __syncthreads();
    for (int j = e0 + tid; j < e1; j += 256) atomicAdd(&h[pairs[j] >> 24], 1);
    __syncthreads();
    int v = h[tid];
    s[tid] = v;
    __syncthreads();
    for (int off = 1; off < 256; off <<= 1) {
        int u = (tid >= off) ? s[tid - off] : 0;
        __syncthreads();
        s[tid] += u;
        __syncthreads();
    }
    int excl = s[tid] - v;
    if (d0 + tid < N) rowptr[d0 + tid] = e0 + excl;
    __syncthreads();
    h[tid] = e0 + excl;
    __syncthreads();
    for (int j = e0 + tid; j < e1; j += 256) {
        uint_t p = pairs[j];
        int pos = atomicAdd(&h[p >> 24], 1);
        csr[pos] = (int)(p & 0xffffffu);
    }
}

// ---------------- P4: SAGE mean aggregation, two L2-resident channel-half passes ----
// 16-lane group per node; per pass, sub-halves of 8 lanes process 2 edges/iter;
// lane covers 4 channels (4 B fp8). Active xq window per pass = 3.2 MB < L2.

__global__ __launch_bounds__(256) void k_gather(const int* __restrict__ rowptr, const int* __restrict__ csr,
                                                const unsigned char* __restrict__ xq,
                                                ushort_t* __restrict__ aggh, int N) {
    __shared__ int scr[256];
    int tid = threadIdx.x;
    int l = tid & 15, g = tid >> 4;
    int i = blockIdx.x * 16 + g;
    if (i >= N) return;
    int r0 = rowptr[i], r1 = rowptr[i + 1];
    int sub = l >> 3, lc = l & 7;
    float dn = 1.0f / fmaxf((float)(r1 - r0), 1.0f);

    #pragma unroll
    for (int p = 0; p < 2; ++p) {
        const char* xb = (const char*)xq + p * 32 + lc * 4;
        float a0 = 0.f, a1 = 0.f, a2 = 0.f, a3 = 0.f;
        for (int bb = r0; bb < r1; bb += 16) {
            int idx = bb + l;
            int src = (idx < r1) ? csr[idx] : N;      // N = zero row
            scr[tid] = src << 6;                      // 64 B fp8 row offset
            uint4 q0 = *(const uint4*)&scr[g * 16 + 0];
            uint4 q1 = *(const uint4*)&scr[g * 16 + 4];
            uint4 q2 = *(const uint4*)&scr[g * 16 + 8];
            uint4 q3 = *(const uint4*)&scr[g * 16 + 12];
#define HSTEP(oa, ob) { \
            uint_t off = sub ? (ob) : (oa); \
            uint_t u = *(const uint_t*)(xb + off); \
            f32x2 p0 = __builtin_amdgcn_cvt_pk_f32_fp8((int)u, false); \
            f32x2 p1 = __builtin_amdgcn_cvt_pk_f32_fp8((int)u, true); \
            a0 += p0.x; a1 += p0.y; a2 += p1.x; a3 += p1.y; }
            HSTEP(q0.x, q0.y) HSTEP(q0.z, q0.w)
            HSTEP(q1.x, q1.y) HSTEP(q1.z, q1.w)
            HSTEP(q2.x, q2.y) HSTEP(q2.z, q2.w)
            HSTEP(q3.x, q3.y) HSTEP(q3.z, q3.w)
#undef HSTEP
        }
        // combine even/odd-edge sub-halves (xor 8 stays inside the 16-group)
        a0 += __shfl_xor(a0, 8, 64);
        a1 += __shfl_xor(a1, 8, 64);
        a2 += __shfl_xor(a2, 8, 64);
        a3 += __shfl_xor(a3, 8, 64);
        if (sub == 0) {
            ushort4 o = { f2bf(a0 * dn), f2bf(a1 * dn), f2bf(a2 * dn), f2bf(a3 * dn) };
            *(ushort4*)(aggh + (size_t)i * 64 + p * 32 + lc * 4) = o;
        }
    }
}

// ---------------- P5: MFMA node GEMMs + attention scores ----------------

__global__ __launch_bounds__(256) void k_gemm(const ushort_t* __restrict__ aggh, const ushort_t* __restrict__ xh,
                                              const ushort_t* __restrict__ Wlrt, const ushort_t* __restrict__ Wgt,
                                              const float* __restrict__ b1,
                                              const float* __restrict__ att_src, const float* __restrict__ att_dst,
                                              unsigned char* __restrict__ zq, float* __restrict__ a_s,
                                              float* __restrict__ a_d, int N) {
    __shared__ ushort_t Wls[64 * 136];
    __shared__ ushort_t Wgs[32 * 72];
    __shared__ ushort_t hs[64 * 136];
    int tid = threadIdx.x;
    for (int t = tid; t < 64 * 16; t += 256) {
        int n = t >> 4, cq = t & 15;
        *(uint4*)(&Wls[n * 136 + cq * 8]) = *(const uint4*)(&Wlrt[n * 128 + cq * 8]);
    }
    for (int t = tid; t < 32 * 8; t += 256) {
        int n = t >> 3, cq = t & 7;
        *(uint4*)(&Wgs[n * 72 + cq * 8]) = *(const uint4*)(&Wgt[n * 64 + cq * 8]);
    }
    __syncthreads();

    int w = tid >> 6, lane = tid & 63;
    int c = lane & 15, quad = lane >> 4;
    int m0 = blockIdx.x * 64 + w * 16;
    int row = m0 + c;
    bool rowok = row < N;

    f32x4 acc[4] = {};
    #pragma unroll
    for (int kk = 0; kk < 4; ++kk) {
        const ushort_t* Abase = (kk < 2) ? aggh : xh;
        int koff = (kk & 1) * 32 + quad * 8;
        short8 a = {};
        if (rowok) a = *(const short8*)(Abase + (size_t)row * 64 + koff);
        #pragma unroll
        for (int nb = 0; nb < 4; ++nb) {
            short8 b = *(const short8*)(&Wls[(nb * 16 + c) * 136 + kk * 32 + quad * 8]);
            acc[nb] = __builtin_amdgcn_mfma_f32_16x16x32_bf16(a, b, acc[nb], 0, 0, 0);
        }
    }
    ushort_t* hw = &hs[w * 16 * 136];
    #pragma unroll
    for (int nb = 0; nb < 4; ++nb) {
        float bb = b1[nb * 16 + c];
        #pragma unroll
        for (int r = 0; r < 4; ++r) {
            float h = acc[nb][r] + bb;
            hw[(quad * 4 + r) * 136 + nb * 16 + c] = f2bf(fmaxf(h, 0.f));
        }
    }
    f32x4 acc2[2] = {};
    #pragma unroll
    for (int kk = 0; kk < 2; ++kk) {
        short8 a = *(const short8*)(&hw[c * 136 + kk * 32 + quad * 8]);
        #pragma unroll
        for (int nb = 0; nb < 2; ++nb) {
            short8 b = *(const short8*)(&Wgs[(nb * 16 + c) * 72 + kk * 32 + quad * 8]);
            acc2[nb] = __builtin_amdgcn_mfma_f32_16x16x32_bf16(a, b, acc2[nb], 0, 0, 0);
        }
    }
    float as0 = att_src[c], as1 = att_src[16 + c];
    float ad0 = att_dst[c], ad1 = att_dst[16 + c];
    #pragma unroll
    for (int r = 0; r < 4; ++r) {
        int grow = m0 + quad * 4 + r;
        float z0 = acc2[0][r], z1 = acc2[1][r];
        float ps = z0 * as0 + z1 * as1;
        float pd = z0 * ad0 + z1 * ad1;
        #pragma unroll
        for (int off = 8; off; off >>= 1) {
            ps += __shfl_xor(ps, off, 64);
            pd += __shfl_xor(pd, off, 64);
        }
        if (grow < N) {
            int r8 = __builtin_amdgcn_cvt_pk_fp8_f32(z0, z1, 0, false);
            unsigned char* zrow = zq + (size_t)grow * 32;
            zrow[c] = (unsigned char)(r8 & 0xff);
            zrow[16 + c] = (unsigned char)((r8 >> 8) & 0xff);
            if (c == 0) { a_s[grow] = ps; a_d[grow] = pd; }
        }
    }
}

// ---------------- P6: GAT softmax aggregation + bias + log_softmax ----------------
// 16-lane group per node; LDS-staged (offset, weight); zq (3.2 MB) is L2-resident.

__global__ __launch_bounds__(256) void k_gat(const unsigned char* __restrict__ zq, const float* __restrict__ a_s,
                                             const float* __restrict__ a_d, const int* __restrict__ rowptr,
                                             const int* __restrict__ csr, const float* __restrict__ b2,
                                             float* __restrict__ out, int N) {
    __shared__ uint2 scr[256];
    int tid = threadIdx.x;
    int l = tid & 15, g = tid >> 4;
    int i = blockIdx.x * 16 + g;
    if (i >= N) return;
    int r0 = rowptr[i], r1 = rowptr[i + 1];
    float adi = a_d[i], asi = a_s[i];
    const char* zb = (const char*)zq + l * 2;
    float accx = 0.f, accy = 0.f, dsum = 0.f;

    for (int bb = r0; bb < r1; bb += 16) {
        int idx = bb + l;
        bool valid = idx < r1;
        int s_l = valid ? csr[idx] : N;           // N = zero row
        float w_l = 0.f;
        if (valid) {
            float e = a_s[s_l] + adi;
            e = fmaxf(e, 0.2f * e);               // leaky_relu
            w_l = __expf(e);
            dsum += w_l;
        }
        scr[tid] = make_uint2((uint_t)(s_l << 5), __float_as_uint(w_l));
        #pragma unroll
        for (int r = 0; r < 8; ++r) {
            uint4 q = *(const uint4*)&scr[g * 16 + r * 2];
            {
                uint_t u = *(const ushort_t*)(zb + q.x);
                f32x2 p = __builtin_amdgcn_cvt_pk_f32_fp8((int)u, false);
                float w = __uint_as_float(q.y);
                accx += w * p.x; accy += w * p.y;
            }
            {
                uint_t u = *(const ushort_t*)(zb + q.z);
                f32x2 p = __builtin_amdgcn_cvt_pk_f32_fp8((int)u, false);
                float w = __uint_as_float(q.w);
                accx += w * p.x; accy += w * p.y;
            }
        }
    }
    #pragma unroll
    for (int off = 8; off; off >>= 1) dsum += __shfl_xor(dsum, off, 64);
    float es = asi + adi; es = fmaxf(es, 0.2f * es);
    float wse = __expf(es);
    float denom = dsum + wse;
    uint_t us = *(const ushort_t*)((const char*)zq + (size_t)i * 32 + l * 2);
    f32x2 pself = __builtin_amdgcn_cvt_pk_f32_fp8((int)us, false);
    accx += wse * pself.x;
    accy += wse * pself.y;

    float rden = 1.0f / denom;
    float o0 = accx * rden + b2[l * 2];
    float o1 = accy * rden + b2[l * 2 + 1];
    float m2 = fmaxf(o0, o1);
    #pragma unroll
    for (int off = 8; off; off >>= 1) m2 = fmaxf(m2, __shfl_xor(m2, off, 64));
    float ssum = __expf(o0 - m2) + __expf(o1 - m2);
    #pragma unroll
    for (int off = 8; off; off >>= 1) ssum += __shfl_xor(ssum, off, 64);
    float lg = m2 + __logf(ssum);
    float2 r = { o0 - lg, o1 - lg };
    *(float2*)(out + (size_t)i * 32 + l * 2) = r;
}

// ---------------- host launch ----------------

extern "C" void kernel_launch(void* const* d_in, const int* in_sizes, int n_in,
                              void* d_out, int out_size, void* d_ws, size_t ws_size,
                              hipStream_t stream) {
    const float* x       = (const float*)d_in[0];
    const int*   ei      = (const int*)d_in[1];
    const float* Wl      = (const float*)d_in[2];
    const float* Wr      = (const float*)d_in[3];
    const float* b1      = (const float*)d_in[4];
    const float* Wg      = (const float*)d_in[5];
    const float* att_src = (const float*)d_in[6];
    const float* att_dst = (const float*)d_in[7];
    const float* b2      = (const float*)d_in[8];
    float* out = (float*)d_out;

    int N = in_sizes[0] / 64;
    int E = in_sizes[1] / 2;
    int NB = (N + 255) >> 8;

    char* ws = (char*)d_ws;
    size_t off = 0;
    auto alloc = [&](size_t bytes) { size_t r = off; off += (bytes + 255) & ~(size_t)255; return r; };
    int* tot       = (int*)(ws + alloc((size_t)(NB + 1) * 4));
    int* base      = (int*)(ws + alloc((size_t)(NB + 1) * 4));
    int* gofs      = (int*)(ws + alloc((size_t)(NB + 1) * 4));
    int* rowptr    = (int*)(ws + alloc((size_t)(N + 1) * 4));
    uint_t* pairs  = (uint_t*)(ws + alloc((size_t)E * 4));
    int* csr       = (int*)(ws + alloc((size_t)E * 4));
    ushort_t* xh   = (ushort_t*)(ws + alloc((size_t)N * 64 * 2));
    unsigned char* xq = (unsigned char*)(ws + alloc((size_t)(N + 1) * 64));
    ushort_t* aggh = (ushort_t*)(ws + alloc((size_t)N * 64 * 2));
    unsigned char* zq = (unsigned char*)(ws + alloc((size_t)(N + 1) * 32));
    float* a_s     = (float*)(ws + alloc((size_t)N * 4));
    float* a_d     = (float*)(ws + alloc((size_t)N * 4));
    ushort_t* Wlrt = (ushort_t*)(ws + alloc(64 * 128 * 2));
    ushort_t* Wgt  = (ushort_t*)(ws + alloc(32 * 64 * 2));

    (void)hipMemsetAsync(tot, 0, (size_t)NB * 4, stream);

    int nchunk = (E + PART_CHUNK - 1) / PART_CHUNK;
    int n4 = N * 64 / 4;
    int gpre = (n4 + 255) / 256;
    if (gpre < 545) gpre = 545;
    k_pre    <<<gpre, 256, 0, stream>>>(x, xh, xq, ei, tot, Wl, Wr, Wg, Wlrt, Wgt, zq, n4, E, NB, N, nchunk);
    k_scan   <<<1, 256, 0, stream>>>(tot, base, gofs, rowptr, NB, E, N);
    k_part   <<<nchunk, 256, 0, stream>>>(ei, gofs, pairs, E, NB);
    k_csr    <<<NB, 256, 0, stream>>>(pairs, base, rowptr, csr, N);
    k_gather <<<(N + 15) / 16, 256, 0, stream>>>(rowptr, csr, xq, aggh, N);
    k_gemm   <<<(N + 63) / 64, 256, 0, stream>>>(aggh, xh, Wlrt, Wgt, b1, att_src, att_dst, zq, a_s, a_d, N);
    k_gat    <<<(N + 15) / 16, 256, 0, stream>>>(zq, a_s, a_d, rowptr, csr, b2, out, N);
}

// Round 11
// 219.565 us; speedup vs baseline: 1.0247x; 1.0247x over previous
//
#include <hip/hip_runtime.h>
#include <cstdint>
#include <cstddef>

// GNN: SAGEConv(mean) + GATConv(1 head, self-loops) + log_softmax
// CSR via two-level counting sort. Edge kernels: 16-lane-group per node,
// LDS-staged offsets, fp8 e4m3 rows, zero-row branchless tails.
// k_gather: two channel-half passes (3.2 MB window fits per-XCD L2) [R10 win].
// PART_CHUNK=4096: k_part needs TLP (R10 lesson: 98 blocks = 51 us disaster).

typedef unsigned short ushort_t;
typedef unsigned int uint_t;
typedef __attribute__((ext_vector_type(8))) short short8;
typedef __attribute__((ext_vector_type(4))) float f32x4;
typedef __attribute__((ext_vector_type(2))) float f32x2;

__device__ inline ushort_t f2bf(float f) {
    uint_t u = __float_as_uint(f);
    uint_t r = (u + 0x7fffu + ((u >> 16) & 1u)) >> 16;   // RTNE
    return (ushort_t)r;
}

#define PART_CHUNK 4096   // edges per block in cnt / k_part (391 blocks)

// ---------------- P0: cvt x -> bf16+fp8, weights -> bf16^T, bucket counts ----------------

__global__ __launch_bounds__(256) void k_pre(const float* __restrict__ x, ushort_t* __restrict__ xh,
                                             unsigned char* __restrict__ xq,
                                             const int* __restrict__ ei, int* __restrict__ tot,
                                             const float* __restrict__ Wl, const float* __restrict__ Wr,
                                             const float* __restrict__ Wg,
                                             ushort_t* __restrict__ Wlrt, ushort_t* __restrict__ Wgt,
                                             unsigned char* __restrict__ zq,
                                             int n4, int E, int NB, int N, int nchunk) {
    __shared__ int h[512];
    int bid = blockIdx.x, tid = threadIdx.x;
    int idx = bid * 256 + tid;
    if (idx < n4) {
        float4 v = ((const float4*)x)[idx];
        ushort4 o = { f2bf(v.x), f2bf(v.y), f2bf(v.z), f2bf(v.w) };
        ((ushort4*)xh)[idx] = o;
        int r = 0;
        r = __builtin_amdgcn_cvt_pk_fp8_f32(v.x, v.y, r, false);
        r = __builtin_amdgcn_cvt_pk_fp8_f32(v.z, v.w, r, true);
        ((uint_t*)xq)[idx] = (uint_t)r;
    }
    if (bid < nchunk) {                         // block-uniform branch: bucket histogram
        for (int b = tid; b < NB; b += 256) h[b] = 0;
        __syncthreads();
        int b0 = bid * PART_CHUNK;
        int b1 = min(b0 + PART_CHUNK, E);
        for (int j = b0 + tid; j < b1; j += 256) atomicAdd(&h[ei[E + j] >> 8], 1);
        __syncthreads();
        for (int b = tid; b < NB; b += 256) if (h[b]) atomicAdd(&tot[b], h[b]);
    } else if (bid == nchunk) {                 // zero rows (branchless tails elsewhere)
        if (tid < 16) ((uint_t*)(xq + (size_t)N * 64))[tid] = 0;
        if (tid < 8)  ((uint_t*)(zq + (size_t)N * 32))[tid] = 0;
    } else if (bid >= 2048 && bid < 2080) {     // weights -> bf16 transposed [n][k]
        int t = (bid - 2048) * 256 + tid;       // 0..8191
        int n = t >> 7, k = t & 127;
        float v = (k < 64) ? Wl[k * 64 + n] : Wr[(k - 64) * 64 + n];
        Wlrt[n * 128 + k] = f2bf(v);
        if (t < 32 * 64) {
            int n2 = t >> 6, k2 = t & 63;
            Wgt[n2 * 64 + k2] = f2bf(Wg[k2 * 32 + n2]);
        }
    }
}

// ---------------- P1: exclusive scan of bucket totals ----------------

__global__ __launch_bounds__(256) void k_scan(const int* __restrict__ tot, int* __restrict__ base,
                                              int* __restrict__ gofs, int* __restrict__ rowptr,
                                              int NB, int E, int N) {
    __shared__ int t[256];
    int tid = threadIdx.x;
    int v0 = (2 * tid < NB) ? tot[2 * tid] : 0;
    int v1 = (2 * tid + 1 < NB) ? tot[2 * tid + 1] : 0;
    t[tid] = v0 + v1;
    __syncthreads();
    for (int off = 1; off < 256; off <<= 1) {
        int u = (tid >= off) ? t[tid - off] : 0;
        __syncthreads();
        t[tid] += u;
        __syncthreads();
    }
    int pairExcl = (tid > 0) ? t[tid - 1] : 0;
    if (2 * tid < NB)     { base[2 * tid] = pairExcl;          gofs[2 * tid] = pairExcl; }
    if (2 * tid + 1 < NB) { base[2 * tid + 1] = pairExcl + v0; gofs[2 * tid + 1] = pairExcl + v0; }
    if (tid == 0) { rowptr[N] = E; base[NB] = E; }
}

// ---------------- P2: partition (src | (dst&255)<<24) bucket-contiguous ----------------

__global__ __launch_bounds__(256) void k_part(const int* __restrict__ ei, int* __restrict__ gofs,
                                              uint_t* __restrict__ pairs, int E, int NB) {
    __shared__ int h[512];
    __shared__ int ofs[512];
    int tid = threadIdx.x;
    for (int b = tid; b < NB; b += 256) h[b] = 0;
    __syncthreads();
    int b0 = blockIdx.x * PART_CHUNK;
    int b1 = min(b0 + PART_CHUNK, E);
    for (int j = b0 + tid; j < b1; j += 256) atomicAdd(&h[ei[E + j] >> 8], 1);
    __syncthreads();
    for (int b = tid; b < NB; b += 256) ofs[b] = h[b] ? atomicAdd(&gofs[b], h[b]) : 0;
    __syncthreads();
    for (int j = b0 + tid; j < b1; j += 256) {
        int d = ei[E + j], s = ei[j];
        int p = atomicAdd(&ofs[d >> 8], 1);
        pairs[p] = (uint_t)s | ((uint_t)(d & 255) << 24);
    }
}

// ---------------- P3: per-bucket CSR build (windowed, L2-hot) ----------------

__global__ __launch_bounds__(256) void k_csr(const uint_t* __restrict__ pairs, const int* __restrict__ base,
                                             int* __restrict__ rowptr, int* __restrict__ csr, int N) {
    __shared__ int h[256];
    __shared__ int s[256];
    int b = blockIdx.x;
    int d0 = b << 8;
    int e0 = base[b], e1 = base[b + 1];
    int tid = threadIdx.x;
    h[tid] = 0;
    __syncthreads();
    for (int j = e0 + tid; j < e1; j += 256) atomicAdd(&h[pairs[j] >> 24], 1);
    __syncthreads();
    int v = h[tid];
    s[tid] = v;
    __syncthreads();
    for (int off = 1; off < 256; off <<= 1) {
        int u = (tid >= off) ? s[tid - off] : 0;
        __syncthreads();
        s[tid] += u;
        __syncthreads();
    }
    int excl = s[tid] - v;
    if (d0 + tid < N) rowptr[d0 + tid] = e0 + excl;
    __syncthreads();
    h[tid] = e0 + excl;
    __syncthreads();
    for (int j = e0 + tid; j < e1; j += 256) {
        uint_t p = pairs[j];
        int pos = atomicAdd(&h[p >> 24], 1);
        csr[pos] = (int)(p & 0xffffffu);
    }
}

// ---------------- P4: SAGE mean aggregation, two L2-resident channel-half passes ----
// 16-lane group per node; per pass, sub-halves of 8 lanes process 2 edges/iter;
// lane covers 4 channels (4 B fp8). Active xq window per pass = 3.2 MB < L2.

__global__ __launch_bounds__(256) void k_gather(const int* __restrict__ rowptr, const int* __restrict__ csr,
                                                const unsigned char* __restrict__ xq,
                                                ushort_t* __restrict__ aggh, int N) {
    __shared__ int scr[256];
    int tid = threadIdx.x;
    int l = tid & 15, g = tid >> 4;
    int i = blockIdx.x * 16 + g;
    if (i >= N) return;
    int r0 = rowptr[i], r1 = rowptr[i + 1];
    int sub = l >> 3, lc = l & 7;
    float dn = 1.0f / fmaxf((float)(r1 - r0), 1.0f);

    #pragma unroll
    for (int p = 0; p < 2; ++p) {
        const char* xb = (const char*)xq + p * 32 + lc * 4;
        float a0 = 0.f, a1 = 0.f, a2 = 0.f, a3 = 0.f;
        for (int bb = r0; bb < r1; bb += 16) {
            int idx = bb + l;
            int src = (idx < r1) ? csr[idx] : N;      // N = zero row
            scr[tid] = src << 6;                      // 64 B fp8 row offset
            uint4 q0 = *(const uint4*)&scr[g * 16 + 0];
            uint4 q1 = *(const uint4*)&scr[g * 16 + 4];
            uint4 q2 = *(const uint4*)&scr[g * 16 + 8];
            uint4 q3 = *(const uint4*)&scr[g * 16 + 12];
#define HSTEP(oa, ob) { \
            uint_t off = sub ? (ob) : (oa); \
            uint_t u = *(const uint_t*)(xb + off); \
            f32x2 p0 = __builtin_amdgcn_cvt_pk_f32_fp8((int)u, false); \
            f32x2 p1 = __builtin_amdgcn_cvt_pk_f32_fp8((int)u, true); \
            a0 += p0.x; a1 += p0.y; a2 += p1.x; a3 += p1.y; }
            HSTEP(q0.x, q0.y) HSTEP(q0.z, q0.w)
            HSTEP(q1.x, q1.y) HSTEP(q1.z, q1.w)
            HSTEP(q2.x, q2.y) HSTEP(q2.z, q2.w)
            HSTEP(q3.x, q3.y) HSTEP(q3.z, q3.w)
#undef HSTEP
        }
        // combine even/odd-edge sub-halves (xor 8 stays inside the 16-group)
        a0 += __shfl_xor(a0, 8, 64);
        a1 += __shfl_xor(a1, 8, 64);
        a2 += __shfl_xor(a2, 8, 64);
        a3 += __shfl_xor(a3, 8, 64);
        if (sub == 0) {
            ushort4 o = { f2bf(a0 * dn), f2bf(a1 * dn), f2bf(a2 * dn), f2bf(a3 * dn) };
            *(ushort4*)(aggh + (size_t)i * 64 + p * 32 + lc * 4) = o;
        }
    }
}

// ---------------- P5: MFMA node GEMMs + attention scores ----------------

__global__ __launch_bounds__(256) void k_gemm(const ushort_t* __restrict__ aggh, const ushort_t* __restrict__ xh,
                                              const ushort_t* __restrict__ Wlrt, const ushort_t* __restrict__ Wgt,
                                              const float* __restrict__ b1,
                                              const float* __restrict__ att_src, const float* __restrict__ att_dst,
                                              unsigned char* __restrict__ zq, float* __restrict__ a_s,
                                              float* __restrict__ a_d, int N) {
    __shared__ ushort_t Wls[64 * 136];
    __shared__ ushort_t Wgs[32 * 72];
    __shared__ ushort_t hs[64 * 136];
    int tid = threadIdx.x;
    for (int t = tid; t < 64 * 16; t += 256) {
        int n = t >> 4, cq = t & 15;
        *(uint4*)(&Wls[n * 136 + cq * 8]) = *(const uint4*)(&Wlrt[n * 128 + cq * 8]);
    }
    for (int t = tid; t < 32 * 8; t += 256) {
        int n = t >> 3, cq = t & 7;
        *(uint4*)(&Wgs[n * 72 + cq * 8]) = *(const uint4*)(&Wgt[n * 64 + cq * 8]);
    }
    __syncthreads();

    int w = tid >> 6, lane = tid & 63;
    int c = lane & 15, quad = lane >> 4;
    int m0 = blockIdx.x * 64 + w * 16;
    int row = m0 + c;
    bool rowok = row < N;

    f32x4 acc[4] = {};
    #pragma unroll
    for (int kk = 0; kk < 4; ++kk) {
        const ushort_t* Abase = (kk < 2) ? aggh : xh;
        int koff = (kk & 1) * 32 + quad * 8;
        short8 a = {};
        if (rowok) a = *(const short8*)(Abase + (size_t)row * 64 + koff);
        #pragma unroll
        for (int nb = 0; nb < 4; ++nb) {
            short8 b = *(const short8*)(&Wls[(nb * 16 + c) * 136 + kk * 32 + quad * 8]);
            acc[nb] = __builtin_amdgcn_mfma_f32_16x16x32_bf16(a, b, acc[nb], 0, 0, 0);
        }
    }
    ushort_t* hw = &hs[w * 16 * 136];
    #pragma unroll
    for (int nb = 0; nb < 4; ++nb) {
        float bb = b1[nb * 16 + c];
        #pragma unroll
        for (int r = 0; r < 4; ++r) {
            float h = acc[nb][r] + bb;
            hw[(quad * 4 + r) * 136 + nb * 16 + c] = f2bf(fmaxf(h, 0.f));
        }
    }
    f32x4 acc2[2] = {};
    #pragma unroll
    for (int kk = 0; kk < 2; ++kk) {
        short8 a = *(const short8*)(&hw[c * 136 + kk * 32 + quad * 8]);
        #pragma unroll
        for (int nb = 0; nb < 2; ++nb) {
            short8 b = *(const short8*)(&Wgs[(nb * 16 + c) * 72 + kk * 32 + quad * 8]);
            acc2[nb] = __builtin_amdgcn_mfma_f32_16x16x32_bf16(a, b, acc2[nb], 0, 0, 0);
        }
    }
    float as0 = att_src[c], as1 = att_src[16 + c];
    float ad0 = att_dst[c], ad1 = att_dst[16 + c];
    #pragma unroll
    for (int r = 0; r < 4; ++r) {
        int grow = m0 + quad * 4 + r;
        float z0 = acc2[0][r], z1 = acc2[1][r];
        float ps = z0 * as0 + z1 * as1;
        float pd = z0 * ad0 + z1 * ad1;
        #pragma unroll
        for (int off = 8; off; off >>= 1) {
            ps += __shfl_xor(ps, off, 64);
            pd += __shfl_xor(pd, off, 64);
        }
        if (grow < N) {
            int r8 = __builtin_amdgcn_cvt_pk_fp8_f32(z0, z1, 0, false);
            unsigned char* zrow = zq + (size_t)grow * 32;
            zrow[c] = (unsigned char)(r8 & 0xff);
            zrow[16 + c] = (unsigned char)((r8 >> 8) & 0xff);
            if (c == 0) { a_s[grow] = ps; a_d[grow] = pd; }
        }
    }
}

// ---------------- P6: GAT softmax aggregation + bias + log_softmax ----------------
// 16-lane group per node; LDS-staged (offset, weight); zq (3.2 MB) is L2-resident.

__global__ __launch_bounds__(256) void k_gat(const unsigned char* __restrict__ zq, const float* __restrict__ a_s,
                                             const float* __restrict__ a_d, const int* __restrict__ rowptr,
                                             const int* __restrict__ csr, const float* __restrict__ b2,
                                             float* __restrict__ out, int N) {
    __shared__ uint2 scr[256];
    int tid = threadIdx.x;
    int l = tid & 15, g = tid >> 4;
    int i = blockIdx.x * 16 + g;
    if (i >= N) return;
    int r0 = rowptr[i], r1 = rowptr[i + 1];
    float adi = a_d[i], asi = a_s[i];
    const char* zb = (const char*)zq + l * 2;
    float accx = 0.f, accy = 0.f, dsum = 0.f;

    for (int bb = r0; bb < r1; bb += 16) {
        int idx = bb + l;
        bool valid = idx < r1;
        int s_l = valid ? csr[idx] : N;           // N = zero row
        float w_l = 0.f;
        if (valid) {
            float e = a_s[s_l] + adi;
            e = fmaxf(e, 0.2f * e);               // leaky_relu
            w_l = __expf(e);
            dsum += w_l;
        }
        scr[tid] = make_uint2((uint_t)(s_l << 5), __float_as_uint(w_l));
        #pragma unroll
        for (int r = 0; r < 8; ++r) {
            uint4 q = *(const uint4*)&scr[g * 16 + r * 2];
            {
                uint_t u = *(const ushort_t*)(zb + q.x);
                f32x2 p = __builtin_amdgcn_cvt_pk_f32_fp8((int)u, false);
                float w = __uint_as_float(q.y);
                accx += w * p.x; accy += w * p.y;
            }
            {
                uint_t u = *(const ushort_t*)(zb + q.z);
                f32x2 p = __builtin_amdgcn_cvt_pk_f32_fp8((int)u, false);
                float w = __uint_as_float(q.w);
                accx += w * p.x; accy += w * p.y;
            }
        }
    }
    #pragma unroll
    for (int off = 8; off; off >>= 1) dsum += __shfl_xor(dsum, off, 64);
    float es = asi + adi; es = fmaxf(es, 0.2f * es);
    float wse = __expf(es);
    float denom = dsum + wse;
    uint_t us = *(const ushort_t*)((const char*)zq + (size_t)i * 32 + l * 2);
    f32x2 pself = __builtin_amdgcn_cvt_pk_f32_fp8((int)us, false);
    accx += wse * pself.x;
    accy += wse * pself.y;

    float rden = 1.0f / denom;
    float o0 = accx * rden + b2[l * 2];
    float o1 = accy * rden + b2[l * 2 + 1];
    float m2 = fmaxf(o0, o1);
    #pragma unroll
    for (int off = 8; off; off >>= 1) m2 = fmaxf(m2, __shfl_xor(m2, off, 64));
    float ssum = __expf(o0 - m2) + __expf(o1 - m2);
    #pragma unroll
    for (int off = 8; off; off >>= 1) ssum += __shfl_xor(ssum, off, 64);
    float lg = m2 + __logf(ssum);
    float2 r = { o0 - lg, o1 - lg };
    *(float2*)(out + (size_t)i * 32 + l * 2) = r;
}

// ---------------- host launch ----------------

extern "C" void kernel_launch(void* const* d_in, const int* in_sizes, int n_in,
                              void* d_out, int out_size, void* d_ws, size_t ws_size,
                              hipStream_t stream) {
    const float* x       = (const float*)d_in[0];
    const int*   ei      = (const int*)d_in[1];
    const float* Wl      = (const float*)d_in[2];
    const float* Wr      = (const float*)d_in[3];
    const float* b1      = (const float*)d_in[4];
    const float* Wg      = (const float*)d_in[5];
    const float* att_src = (const float*)d_in[6];
    const float* att_dst = (const float*)d_in[7];
    const float* b2      = (const float*)d_in[8];
    float* out = (float*)d_out;

    int N = in_sizes[0] / 64;
    int E = in_sizes[1] / 2;
    int NB = (N + 255) >> 8;

    char* ws = (char*)d_ws;
    size_t off = 0;
    auto alloc = [&](size_t bytes) { size_t r = off; off += (bytes + 255) & ~(size_t)255; return r; };
    int* tot       = (int*)(ws + alloc((size_t)(NB + 1) * 4));
    int* base      = (int*)(ws + alloc((size_t)(NB + 1) * 4));
    int* gofs      = (int*)(ws + alloc((size_t)(NB + 1) * 4));
    int* rowptr    = (int*)(ws + alloc((size_t)(N + 1) * 4));
    uint_t* pairs  = (uint_t*)(ws + alloc((size_t)E * 4));
    int* csr       = (int*)(ws + alloc((size_t)E * 4));
    ushort_t* xh   = (ushort_t*)(ws + alloc((size_t)N * 64 * 2));
    unsigned char* xq = (unsigned char*)(ws + alloc((size_t)(N + 1) * 64));
    ushort_t* aggh = (ushort_t*)(ws + alloc((size_t)N * 64 * 2));
    unsigned char* zq = (unsigned char*)(ws + alloc((size_t)(N + 1) * 32));
    float* a_s     = (float*)(ws + alloc((size_t)N * 4));
    float* a_d     = (float*)(ws + alloc((size_t)N * 4));
    ushort_t* Wlrt = (ushort_t*)(ws + alloc(64 * 128 * 2));
    ushort_t* Wgt  = (ushort_t*)(ws + alloc(32 * 64 * 2));

    (void)hipMemsetAsync(tot, 0, (size_t)NB * 4, stream);

    int nchunk = (E + PART_CHUNK - 1) / PART_CHUNK;   // 391 < 2048
    int n4 = N * 64 / 4;
    int gpre = (n4 + 255) / 256;
    if (gpre < 2081) gpre = 2081;
    k_pre    <<<gpre, 256, 0, stream>>>(x, xh, xq, ei, tot, Wl, Wr, Wg, Wlrt, Wgt, zq, n4, E, NB, N, nchunk);
    k_scan   <<<1, 256, 0, stream>>>(tot, base, gofs, rowptr, NB, E, N);
    k_part   <<<nchunk, 256, 0, stream>>>(ei, gofs, pairs, E, NB);
    k_csr    <<<NB, 256, 0, stream>>>(pairs, base, rowptr, csr, N);
    k_gather <<<(N + 15) / 16, 256, 0, stream>>>(rowptr, csr, xq, aggh, N);
    k_gemm   <<<(N + 63) / 64, 256, 0, stream>>>(aggh, xh, Wlrt, Wgt, b1, att_src, att_dst, zq, a_s, a_d, N);
    k_gat    <<<(N + 15) / 16, 256, 0, stream>>>(zq, a_s, a_d, rowptr, csr, b2, out, N);
}

// Round 12
// 203.587 us; speedup vs baseline: 1.1052x; 1.0785x over previous
//
#include <hip/hip_runtime.h>
#include <cstdint>
#include <cstddef>

// GNN: SAGEConv(mean) + GATConv(1 head, self-loops) + log_softmax
// CSR via two-level counting sort (PART_CHUNK=8192 — measured optimum).
// Edge kernels: 16-lane-group per node, LDS-staged offsets, fp8 e4m3 rows,
// zero-row branchless tails, 8-lanes-per-edge wide loads (uint2 / uint).
// MFMA node GEMMs. Single-pass gather (R10/R11 lesson: L2 line granularity
// defeats channel-half windowing).

typedef unsigned short ushort_t;
typedef unsigned int uint_t;
typedef __attribute__((ext_vector_type(8))) short short8;
typedef __attribute__((ext_vector_type(4))) float f32x4;
typedef __attribute__((ext_vector_type(2))) float f32x2;

__device__ inline ushort_t f2bf(float f) {
    uint_t u = __float_as_uint(f);
    uint_t r = (u + 0x7fffu + ((u >> 16) & 1u)) >> 16;   // RTNE
    return (ushort_t)r;
}
__device__ inline uint_t pkbf(float a, float b) {
    return (uint_t)f2bf(a) | ((uint_t)f2bf(b) << 16);
}

#define PART_CHUNK 8192   // edges per block in cnt / k_part (196 blocks)

// ---------------- P0: cvt x -> bf16+fp8, weights -> bf16^T, bucket counts ----------------

__global__ __launch_bounds__(256) void k_pre(const float* __restrict__ x, ushort_t* __restrict__ xh,
                                             unsigned char* __restrict__ xq,
                                             const int* __restrict__ ei, int* __restrict__ tot,
                                             const float* __restrict__ Wl, const float* __restrict__ Wr,
                                             const float* __restrict__ Wg,
                                             ushort_t* __restrict__ Wlrt, ushort_t* __restrict__ Wgt,
                                             unsigned char* __restrict__ zq,
                                             int n4, int E, int NB, int N, int nchunk) {
    __shared__ int h[512];
    int bid = blockIdx.x, tid = threadIdx.x;
    int idx = bid * 256 + tid;
    if (idx < n4) {
        float4 v = ((const float4*)x)[idx];
        ushort4 o = { f2bf(v.x), f2bf(v.y), f2bf(v.z), f2bf(v.w) };
        ((ushort4*)xh)[idx] = o;
        int r = 0;
        r = __builtin_amdgcn_cvt_pk_fp8_f32(v.x, v.y, r, false);
        r = __builtin_amdgcn_cvt_pk_fp8_f32(v.z, v.w, r, true);
        ((uint_t*)xq)[idx] = (uint_t)r;
    }
    if (bid < nchunk) {                         // block-uniform branch: bucket histogram
        for (int b = tid; b < NB; b += 256) h[b] = 0;
        __syncthreads();
        int b0 = bid * PART_CHUNK;
        int b1 = min(b0 + PART_CHUNK, E);
        for (int j = b0 + tid; j < b1; j += 256) atomicAdd(&h[ei[E + j] >> 8], 1);
        __syncthreads();
        for (int b = tid; b < NB; b += 256) if (h[b]) atomicAdd(&tot[b], h[b]);
    } else if (bid == nchunk) {                 // zero rows (branchless tails elsewhere)
        if (tid < 16) ((uint_t*)(xq + (size_t)N * 64))[tid] = 0;
        if (tid < 8)  ((uint_t*)(zq + (size_t)N * 32))[tid] = 0;
    } else if (bid >= 512 && bid < 544) {       // weights -> bf16 transposed [n][k]
        int t = (bid - 512) * 256 + tid;        // 0..8191
        int n = t >> 7, k = t & 127;
        float v = (k < 64) ? Wl[k * 64 + n] : Wr[(k - 64) * 64 + n];
        Wlrt[n * 128 + k] = f2bf(v);
        if (t < 32 * 64) {
            int n2 = t >> 6, k2 = t & 63;
            Wgt[n2 * 64 + k2] = f2bf(Wg[k2 * 32 + n2]);
        }
    }
}

// ---------------- P1: exclusive scan of bucket totals ----------------

__global__ __launch_bounds__(256) void k_scan(const int* __restrict__ tot, int* __restrict__ base,
                                              int* __restrict__ gofs, int* __restrict__ rowptr,
                                              int NB, int E, int N) {
    __shared__ int t[256];
    int tid = threadIdx.x;
    int v0 = (2 * tid < NB) ? tot[2 * tid] : 0;
    int v1 = (2 * tid + 1 < NB) ? tot[2 * tid + 1] : 0;
    t[tid] = v0 + v1;
    __syncthreads();
    for (int off = 1; off < 256; off <<= 1) {
        int u = (tid >= off) ? t[tid - off] : 0;
        __syncthreads();
        t[tid] += u;
        __syncthreads();
    }
    int pairExcl = (tid > 0) ? t[tid - 1] : 0;
    if (2 * tid < NB)     { base[2 * tid] = pairExcl;          gofs[2 * tid] = pairExcl; }
    if (2 * tid + 1 < NB) { base[2 * tid + 1] = pairExcl + v0; gofs[2 * tid + 1] = pairExcl + v0; }
    if (tid == 0) { rowptr[N] = E; base[NB] = E; }
}

// ---------------- P2: partition (src | (dst&255)<<24) bucket-contiguous ----------------

__global__ __launch_bounds__(256) void k_part(const int* __restrict__ ei, int* __restrict__ gofs,
                                              uint_t* __restrict__ pairs, int E, int NB) {
    __shared__ int h[512];
    __shared__ int ofs[512];
    int tid = threadIdx.x;
    for (int b = tid; b < NB; b += 256) h[b] = 0;
    __syncthreads();
    int b0 = blockIdx.x * PART_CHUNK;
    int b1 = min(b0 + PART_CHUNK, E);
    for (int j = b0 + tid; j < b1; j += 256) atomicAdd(&h[ei[E + j] >> 8], 1);
    __syncthreads();
    for (int b = tid; b < NB; b += 256) ofs[b] = h[b] ? atomicAdd(&gofs[b], h[b]) : 0;
    __syncthreads();
    for (int j = b0 + tid; j < b1; j += 256) {
        int d = ei[E + j], s = ei[j];
        int p = atomicAdd(&ofs[d >> 8], 1);
        pairs[p] = (uint_t)s | ((uint_t)(d & 255) << 24);
    }
}

// ---------------- P3: per-bucket CSR build (windowed, L2-hot) ----------------

__global__ __launch_bounds__(256) void k_csr(const uint_t* __restrict__ pairs, const int* __restrict__ base,
                                             int* __restrict__ rowptr, int* __restrict__ csr, int N) {
    __shared__ int h[256];
    __shared__ int s[256];
    int b = blockIdx.x;
    int d0 = b << 8;
    int e0 = base[b], e1 = base[b + 1];
    int tid = threadIdx.x;
    h[tid] = 0;
    __syncthreads();
    for (int j = e0 + tid; j < e1; j += 256) atomicAdd(&h[pairs[j] >> 24], 1);
    __syncthreads();
    int v = h[tid];
    s[tid] = v;
    __syncthreads();
    for (int off = 1; off < 256; off <<= 1) {
        int u = (tid >= off) ? s[tid - off] : 0;
        __syncthreads();
        s[tid] += u;
        __syncthreads();
    }
    int excl = s[tid] - v;
    if (d0 + tid < N) rowptr[d0 + tid] = e0 + excl;
    __syncthreads();
    h[tid] = e0 + excl;
    __syncthreads();
    for (int j = e0 + tid; j < e1; j += 256) {
        uint_t p = pairs[j];
        int pos = atomicAdd(&h[p >> 24], 1);
        csr[pos] = (int)(p & 0xffffffu);
    }
}

// ---------------- P4: SAGE mean aggregation ----------------
// 16-lane group per node; sub-halves of 8 lanes take even/odd edges;
// lane covers 8 channels via one uint2 (8 B) load. Single pass.

__global__ __launch_bounds__(256) void k_gather(const int* __restrict__ rowptr, const int* __restrict__ csr,
                                                const unsigned char* __restrict__ xq,
                                                ushort_t* __restrict__ aggh, int N) {
    __shared__ int scr[256];
    int tid = threadIdx.x;
    int l = tid & 15, g = tid >> 4;
    int i = blockIdx.x * 16 + g;
    if (i >= N) return;
    int r0 = rowptr[i], r1 = rowptr[i + 1];
    int sub = l >> 3, lc = l & 7;
    const char* xb = (const char*)xq + lc * 8;
    float a0 = 0.f, a1 = 0.f, a2 = 0.f, a3 = 0.f;
    float a4 = 0.f, a5 = 0.f, a6 = 0.f, a7 = 0.f;
    for (int bb = r0; bb < r1; bb += 16) {
        int idx = bb + l;
        int src = (idx < r1) ? csr[idx] : N;      // N = zero row
        scr[tid] = src << 6;                      // 64 B fp8 row offset
        uint4 q0 = *(const uint4*)&scr[g * 16 + 0];
        uint4 q1 = *(const uint4*)&scr[g * 16 + 4];
        uint4 q2 = *(const uint4*)&scr[g * 16 + 8];
        uint4 q3 = *(const uint4*)&scr[g * 16 + 12];
#define HSTEP(oa, ob) { \
        uint_t off = sub ? (ob) : (oa); \
        uint2 u = *(const uint2*)(xb + off); \
        f32x2 p0 = __builtin_amdgcn_cvt_pk_f32_fp8((int)u.x, false); \
        f32x2 p1 = __builtin_amdgcn_cvt_pk_f32_fp8((int)u.x, true); \
        f32x2 p2 = __builtin_amdgcn_cvt_pk_f32_fp8((int)u.y, false); \
        f32x2 p3 = __builtin_amdgcn_cvt_pk_f32_fp8((int)u.y, true); \
        a0 += p0.x; a1 += p0.y; a2 += p1.x; a3 += p1.y; \
        a4 += p2.x; a5 += p2.y; a6 += p3.x; a7 += p3.y; }
        HSTEP(q0.x, q0.y) HSTEP(q0.z, q0.w)
        HSTEP(q1.x, q1.y) HSTEP(q1.z, q1.w)
        HSTEP(q2.x, q2.y) HSTEP(q2.z, q2.w)
        HSTEP(q3.x, q3.y) HSTEP(q3.z, q3.w)
#undef HSTEP
    }
    // combine even/odd-edge sub-halves (xor 8 stays inside the 16-group)
    a0 += __shfl_xor(a0, 8, 64); a1 += __shfl_xor(a1, 8, 64);
    a2 += __shfl_xor(a2, 8, 64); a3 += __shfl_xor(a3, 8, 64);
    a4 += __shfl_xor(a4, 8, 64); a5 += __shfl_xor(a5, 8, 64);
    a6 += __shfl_xor(a6, 8, 64); a7 += __shfl_xor(a7, 8, 64);
    if (sub == 0) {
        float dn = 1.0f / fmaxf((float)(r1 - r0), 1.0f);
        uint4 o = { pkbf(a0 * dn, a1 * dn), pkbf(a2 * dn, a3 * dn),
                    pkbf(a4 * dn, a5 * dn), pkbf(a6 * dn, a7 * dn) };
        *(uint4*)(aggh + (size_t)i * 64 + lc * 8) = o;
    }
}

// ---------------- P5: MFMA node GEMMs + attention scores ----------------

__global__ __launch_bounds__(256) void k_gemm(const ushort_t* __restrict__ aggh, const ushort_t* __restrict__ xh,
                                              const ushort_t* __restrict__ Wlrt, const ushort_t* __restrict__ Wgt,
                                              const float* __restrict__ b1,
                                              const float* __restrict__ att_src, const float* __restrict__ att_dst,
                                              unsigned char* __restrict__ zq, float* __restrict__ a_s,
                                              float* __restrict__ a_d, int N) {
    __shared__ ushort_t Wls[64 * 136];
    __shared__ ushort_t Wgs[32 * 72];
    __shared__ ushort_t hs[64 * 136];
    int tid = threadIdx.x;
    for (int t = tid; t < 64 * 16; t += 256) {
        int n = t >> 4, cq = t & 15;
        *(uint4*)(&Wls[n * 136 + cq * 8]) = *(const uint4*)(&Wlrt[n * 128 + cq * 8]);
    }
    for (int t = tid; t < 32 * 8; t += 256) {
        int n = t >> 3, cq = t & 7;
        *(uint4*)(&Wgs[n * 72 + cq * 8]) = *(const uint4*)(&Wgt[n * 64 + cq * 8]);
    }
    __syncthreads();

    int w = tid >> 6, lane = tid & 63;
    int c = lane & 15, quad = lane >> 4;
    int m0 = blockIdx.x * 64 + w * 16;
    int row = m0 + c;
    bool rowok = row < N;

    f32x4 acc[4] = {};
    #pragma unroll
    for (int kk = 0; kk < 4; ++kk) {
        const ushort_t* Abase = (kk < 2) ? aggh : xh;
        int koff = (kk & 1) * 32 + quad * 8;
        short8 a = {};
        if (rowok) a = *(const short8*)(Abase + (size_t)row * 64 + koff);
        #pragma unroll
        for (int nb = 0; nb < 4; ++nb) {
            short8 b = *(const short8*)(&Wls[(nb * 16 + c) * 136 + kk * 32 + quad * 8]);
            acc[nb] = __builtin_amdgcn_mfma_f32_16x16x32_bf16(a, b, acc[nb], 0, 0, 0);
        }
    }
    ushort_t* hw = &hs[w * 16 * 136];
    #pragma unroll
    for (int nb = 0; nb < 4; ++nb) {
        float bb = b1[nb * 16 + c];
        #pragma unroll
        for (int r = 0; r < 4; ++r) {
            float h = acc[nb][r] + bb;
            hw[(quad * 4 + r) * 136 + nb * 16 + c] = f2bf(fmaxf(h, 0.f));
        }
    }
    f32x4 acc2[2] = {};
    #pragma unroll
    for (int kk = 0; kk < 2; ++kk) {
        short8 a = *(const short8*)(&hw[c * 136 + kk * 32 + quad * 8]);
        #pragma unroll
        for (int nb = 0; nb < 2; ++nb) {
            short8 b = *(const short8*)(&Wgs[(nb * 16 + c) * 72 + kk * 32 + quad * 8]);
            acc2[nb] = __builtin_amdgcn_mfma_f32_16x16x32_bf16(a, b, acc2[nb], 0, 0, 0);
        }
    }
    float as0 = att_src[c], as1 = att_src[16 + c];
    float ad0 = att_dst[c], ad1 = att_dst[16 + c];
    #pragma unroll
    for (int r = 0; r < 4; ++r) {
        int grow = m0 + quad * 4 + r;
        float z0 = acc2[0][r], z1 = acc2[1][r];
        float ps = z0 * as0 + z1 * as1;
        float pd = z0 * ad0 + z1 * ad1;
        #pragma unroll
        for (int off = 8; off; off >>= 1) {
            ps += __shfl_xor(ps, off, 64);
            pd += __shfl_xor(pd, off, 64);
        }
        if (grow < N) {
            int r8 = __builtin_amdgcn_cvt_pk_fp8_f32(z0, z1, 0, false);
            unsigned char* zrow = zq + (size_t)grow * 32;
            zrow[c] = (unsigned char)(r8 & 0xff);
            zrow[16 + c] = (unsigned char)((r8 >> 8) & 0xff);
            if (c == 0) { a_s[grow] = ps; a_d[grow] = pd; }
        }
    }
}

// ---------------- P6: GAT softmax aggregation + bias + log_softmax ----------------
// 16-lane group per node; LDS-staged (offset, weight); sub-halves of 8 lanes
// take even/odd edges; lane covers 4 channels via one uint (4 B) load.

__global__ __launch_bounds__(256) void k_gat(const unsigned char* __restrict__ zq, const float* __restrict__ a_s,
                                             const float* __restrict__ a_d, const int* __restrict__ rowptr,
                                             const int* __restrict__ csr, const float* __restrict__ b2,
                                             float* __restrict__ out, int N) {
    __shared__ uint2 scr[256];
    int tid = threadIdx.x;
    int l = tid & 15, g = tid >> 4;
    int i = blockIdx.x * 16 + g;
    if (i >= N) return;
    int r0 = rowptr[i], r1 = rowptr[i + 1];
    float adi = a_d[i], asi = a_s[i];
    int sub = l >> 3, lc = l & 7;
    const char* zb = (const char*)zq + lc * 4;
    float a0 = 0.f, a1 = 0.f, a2 = 0.f, a3 = 0.f, dsum = 0.f;

    for (int bb = r0; bb < r1; bb += 16) {
        int idx = bb + l;
        bool valid = idx < r1;
        int s_l = valid ? csr[idx] : N;           // N = zero row
        float w_l = 0.f;
        if (valid) {
            float e = a_s[s_l] + adi;
            e = fmaxf(e, 0.2f * e);               // leaky_relu
            w_l = __expf(e);
            dsum += w_l;
        }
        scr[tid] = make_uint2((uint_t)(s_l << 5), __float_as_uint(w_l));
        #pragma unroll
        for (int r = 0; r < 8; ++r) {
            uint4 q = *(const uint4*)&scr[g * 16 + r * 2];
            uint_t off = sub ? q.z : q.x;
            float w = __uint_as_float(sub ? q.w : q.y);
            uint_t u = *(const uint_t*)(zb + off);
            f32x2 p0 = __builtin_amdgcn_cvt_pk_f32_fp8((int)u, false);
            f32x2 p1 = __builtin_amdgcn_cvt_pk_f32_fp8((int)u, true);
            a0 += w * p0.x; a1 += w * p0.y;
            a2 += w * p1.x; a3 += w * p1.y;
        }
    }
    #pragma unroll
    for (int off = 8; off; off >>= 1) dsum += __shfl_xor(dsum, off, 64);
    // combine even/odd sub-halves
    a0 += __shfl_xor(a0, 8, 64); a1 += __shfl_xor(a1, 8, 64);
    a2 += __shfl_xor(a2, 8, 64); a3 += __shfl_xor(a3, 8, 64);
    // self loop
    float es = asi + adi; es = fmaxf(es, 0.2f * es);
    float wse = __expf(es);
    float denom = dsum + wse;
    uint_t us = *(const uint_t*)((const char*)zq + (size_t)i * 32 + lc * 4);
    f32x2 s0 = __builtin_amdgcn_cvt_pk_f32_fp8((int)us, false);
    f32x2 s1 = __builtin_amdgcn_cvt_pk_f32_fp8((int)us, true);
    a0 += wse * s0.x; a1 += wse * s0.y;
    a2 += wse * s1.x; a3 += wse * s1.y;

    float rden = 1.0f / denom;
    float o0 = a0 * rden + b2[lc * 4 + 0];
    float o1 = a1 * rden + b2[lc * 4 + 1];
    float o2 = a2 * rden + b2[lc * 4 + 2];
    float o3 = a3 * rden + b2[lc * 4 + 3];
    // log_softmax over 32 channels (8 lanes x 4 ch; subs hold identical data)
    float m2 = fmaxf(fmaxf(o0, o1), fmaxf(o2, o3));
    #pragma unroll
    for (int off = 4; off; off >>= 1) m2 = fmaxf(m2, __shfl_xor(m2, off, 64));
    float ssum = __expf(o0 - m2) + __expf(o1 - m2) + __expf(o2 - m2) + __expf(o3 - m2);
    #pragma unroll
    for (int off = 4; off; off >>= 1) ssum += __shfl_xor(ssum, off, 64);
    float lg = m2 + __logf(ssum);
    if (sub == 0) {
        float4 r = { o0 - lg, o1 - lg, o2 - lg, o3 - lg };
        *(float4*)(out + (size_t)i * 32 + lc * 4) = r;
    }
}

// ---------------- host launch ----------------

extern "C" void kernel_launch(void* const* d_in, const int* in_sizes, int n_in,
                              void* d_out, int out_size, void* d_ws, size_t ws_size,
                              hipStream_t stream) {
    const float* x       = (const float*)d_in[0];
    const int*   ei      = (const int*)d_in[1];
    const float* Wl      = (const float*)d_in[2];
    const float* Wr      = (const float*)d_in[3];
    const float* b1      = (const float*)d_in[4];
    const float* Wg      = (const float*)d_in[5];
    const float* att_src = (const float*)d_in[6];
    const float* att_dst = (const float*)d_in[7];
    const float* b2      = (const float*)d_in[8];
    float* out = (float*)d_out;

    int N = in_sizes[0] / 64;
    int E = in_sizes[1] / 2;
    int NB = (N + 255) >> 8;

    char* ws = (char*)d_ws;
    size_t off = 0;
    auto alloc = [&](size_t bytes) { size_t r = off; off += (bytes + 255) & ~(size_t)255; return r; };
    int* tot       = (int*)(ws + alloc((size_t)(NB + 1) * 4));
    int* base      = (int*)(ws + alloc((size_t)(NB + 1) * 4));
    int* gofs      = (int*)(ws + alloc((size_t)(NB + 1) * 4));
    int* rowptr    = (int*)(ws + alloc((size_t)(N + 1) * 4));
    uint_t* pairs  = (uint_t*)(ws + alloc((size_t)E * 4));
    int* csr       = (int*)(ws + alloc((size_t)E * 4));
    ushort_t* xh   = (ushort_t*)(ws + alloc((size_t)N * 64 * 2));
    unsigned char* xq = (unsigned char*)(ws + alloc((size_t)(N + 1) * 64));
    ushort_t* aggh = (ushort_t*)(ws + alloc((size_t)N * 64 * 2));
    unsigned char* zq = (unsigned char*)(ws + alloc((size_t)(N + 1) * 32));
    float* a_s     = (float*)(ws + alloc((size_t)N * 4));
    float* a_d     = (float*)(ws + alloc((size_t)N * 4));
    ushort_t* Wlrt = (ushort_t*)(ws + alloc(64 * 128 * 2));
    ushort_t* Wgt  = (ushort_t*)(ws + alloc(32 * 64 * 2));

    (void)hipMemsetAsync(tot, 0, (size_t)NB * 4, stream);

    int nchunk = (E + PART_CHUNK - 1) / PART_CHUNK;   // 196
    int n4 = N * 64 / 4;
    int gpre = (n4 + 255) / 256;
    if (gpre < 545) gpre = 545;
    k_pre    <<<gpre, 256, 0, stream>>>(x, xh, xq, ei, tot, Wl, Wr, Wg, Wlrt, Wgt, zq, n4, E, NB, N, nchunk);
    k_scan   <<<1, 256, 0, stream>>>(tot, base, gofs, rowptr, NB, E, N);
    k_part   <<<nchunk, 256, 0, stream>>>(ei, gofs, pairs, E, NB);
    k_csr    <<<NB, 256, 0, stream>>>(pairs, base, rowptr, csr, N);
    k_gather <<<(N + 15) / 16, 256, 0, stream>>>(rowptr, csr, xq, aggh, N);
    k_gemm   <<<(N + 63) / 64, 256, 0, stream>>>(aggh, xh, Wlrt, Wgt, b1, att_src, att_dst, zq, a_s, a_d, N);
    k_gat    <<<(N + 15) / 16, 256, 0, stream>>>(zq, a_s, a_d, rowptr, csr, b2, out, N);
}